// Round 5
// baseline (144.513 us; speedup 1.0000x reference)
//
#include <hip/hip_runtime.h>
#include <stdint.h>

#define NN 4096
#define MM 8192
#define DD 512
#define KT2 16  // 512 / BK, BK = 32

typedef __bf16 bf16x8 __attribute__((ext_vector_type(8)));
typedef __bf16 bf16x4 __attribute__((ext_vector_type(4)));
typedef float f32x4 __attribute__((ext_vector_type(4)));
typedef float f32x16 __attribute__((ext_vector_type(16)));

__device__ __forceinline__ void load_lds16(const void* g, void* l) {
  // async global -> LDS, 16B/lane; LDS dest must be wave-uniform base + lane*16.
  __builtin_amdgcn_global_load_lds(
      (const __attribute__((address_space(1))) unsigned int*)g,
      (__attribute__((address_space(3))) unsigned int*)l, 16, 0, 0);
}

// 4 rows per 256-thread block, one wave per row. Fully-coalesced f32x4 loads,
// bf16x4 stores, exact fp32 row-norm, and out[]=IC init folded in.
__global__ __launch_bounds__(256) void convert_norm_kernel(
    const float* __restrict__ X, const float* __restrict__ SV,
    __bf16* __restrict__ Xb, __bf16* __restrict__ SVb,
    float* __restrict__ x2, float* __restrict__ sv2,
    float* __restrict__ out, const float* __restrict__ IC) {
  int wid = blockIdx.x * 4 + (threadIdx.x >> 6);
  int lane = threadIdx.x & 63;
  const float* src;
  __bf16* dst;
  float* nrm;
  if (wid < NN) {
    src = X + (size_t)wid * DD;
    dst = Xb + (size_t)wid * DD;
    nrm = x2 + wid;
    if (lane == 0) out[wid] = IC[0];
  } else {
    int r = wid - NN;
    src = SV + (size_t)r * DD;
    dst = SVb + (size_t)r * DD;
    nrm = sv2 + r;
  }
  const f32x4* s = (const f32x4*)src;
  f32x4 a = s[lane];
  f32x4 b = s[lane + 64];
  float sum = a.x * a.x + a.y * a.y + a.z * a.z + a.w * a.w +
              b.x * b.x + b.y * b.y + b.z * b.z + b.w * b.w;
  bf16x4 ca = {(__bf16)a.x, (__bf16)a.y, (__bf16)a.z, (__bf16)a.w};
  bf16x4 cb = {(__bf16)b.x, (__bf16)b.y, (__bf16)b.z, (__bf16)b.w};
  *(bf16x4*)(dst + 4 * lane) = ca;
  *(bf16x4*)(dst + 256 + 4 * lane) = cb;
#pragma unroll
  for (int m = 32; m >= 1; m >>= 1) sum += __shfl_xor(sum, m, 64);
  if (lane == 0) *nrm = sum;
}

// Double-buffered GEMM, BK=32: 4 waves (2x2), each a 64x64 sub-tile via 2x2 of
// mfma_f32_32x32x16_bf16. LDS = 2 buffers x (A 8 KB + B 8 KB) = 32 KB ->
// 4 blocks/CU (reg cap: 64 VGPR + 64 AGPR = 128 -> 4 waves/SIMD).
// Pipeline: stage kt+1 into buf^1, compute kt from buf, ONE barrier per kt.
// The barrier's vmcnt(0) drain waits on loads issued a full compute phase
// earlier -> off the critical path.
//
// LDS layout per buffer/matrix: 128 rows x 4 chunks of 16 B, XOR swizzle:
//   P(row, kg) = row*4 + (kg ^ (row & 3))
// Staging: chunk c -> row=c>>2, kg=(c&3)^(row&3); per 8-lane group the global
// addresses permute two 64 B spans (TCC sector granular); LDS dest is
// lane-contiguous (global_load_lds constraint). Fragment ds_read_b128: per
// 8-lane group chunk-addrs mod 8 take 4 distinct values twice -> 2-way = free.
__global__ __launch_bounds__(256, 4) void rbf_gemm_kernel(
    const bf16x8* __restrict__ Xb, const bf16x8* __restrict__ SVb,
    const float* __restrict__ x2, const float* __restrict__ sv2,
    const float* __restrict__ DC, const float* __restrict__ gamma_p,
    float* __restrict__ out) {
  __shared__ bf16x8 As[2][512];  // 2 x 8 KB
  __shared__ bf16x8 Bs[2][512];  // 2 x 8 KB

  const int t = threadIdx.x;
  const int lane = t & 63;
  const int wave = t >> 6;
  const int n0 = blockIdx.x * 128;
  const int m0 = blockIdx.y * 128;

  const int wave_m = wave & 1;   // m-dir of C
  const int wave_n = wave >> 1;  // n-dir of C
  const int l31 = lane & 31;
  const int lhi = lane >> 5;

  // staging: chunks c0 = t, c1 = t + 256 (512 chunks per matrix per kt)
  const int c0 = t;
  const int c1 = t + 256;
  const int r0 = c0 >> 2, k0 = (c0 & 3) ^ (r0 & 3);
  const int r1 = c1 >> 2, k1 = (c1 & 3) ^ (r1 & 3);
  const size_t gA0 = (size_t)(n0 + r0) * 64 + k0;  // chunk index into Xb
  const size_t gA1 = (size_t)(n0 + r1) * 64 + k1;
  const size_t gB0 = (size_t)(m0 + r0) * 64 + k0;
  const size_t gB1 = (size_t)(m0 + r1) * 64 + k1;

  // fragment read bases (chunk index), row&3 == l31&3 for all our row bases
  const int ra4 = (wave_n * 64 + l31) * 4;
  const int rb4 = (wave_m * 64 + l31) * 4;

  f32x16 acc[2][2];
#pragma unroll
  for (int i = 0; i < 2; ++i)
#pragma unroll
    for (int j = 0; j < 2; ++j)
#pragma unroll
      for (int r = 0; r < 16; ++r) acc[i][j][r] = 0.0f;

  // prologue: stage kt=0 into buffer 0
  load_lds16(Xb + gA0, &As[0][c0]);
  load_lds16(Xb + gA1, &As[0][c1]);
  load_lds16(SVb + gB0, &Bs[0][c0]);
  load_lds16(SVb + gB1, &Bs[0][c1]);
  __syncthreads();

#pragma unroll
  for (int kt = 0; kt < KT2; ++kt) {
    const int cur = kt & 1;
    const int nxt = cur ^ 1;
    // stage kt+1 first (loads fly during compute below)
    if (kt + 1 < KT2) {
      const int ko = (kt + 1) * 4;
      load_lds16(Xb + gA0 + ko, &As[nxt][c0]);
      load_lds16(Xb + gA1 + ko, &As[nxt][c1]);
      load_lds16(SVb + gB0 + ko, &Bs[nxt][c0]);
      load_lds16(SVb + gB1 + ko, &Bs[nxt][c1]);
    }
    // compute kt
#pragma unroll
    for (int ks = 0; ks < 2; ++ks) {
      const int kc = ks * 2 + lhi;       // chunk 0..3
      const int sw = kc ^ (l31 & 3);
      bf16x8 af0 = As[cur][ra4 + sw];
      bf16x8 af1 = As[cur][ra4 + 128 + sw];  // +32 rows
      bf16x8 bf0 = Bs[cur][rb4 + sw];
      bf16x8 bf1 = Bs[cur][rb4 + 128 + sw];
      acc[0][0] = __builtin_amdgcn_mfma_f32_32x32x16_bf16(af0, bf0, acc[0][0], 0, 0, 0);
      acc[0][1] = __builtin_amdgcn_mfma_f32_32x32x16_bf16(af0, bf1, acc[0][1], 0, 0, 0);
      acc[1][0] = __builtin_amdgcn_mfma_f32_32x32x16_bf16(af1, bf0, acc[1][0], 0, 0, 0);
      acc[1][1] = __builtin_amdgcn_mfma_f32_32x32x16_bf16(af1, bf1, acc[1][1], 0, 0, 0);
    }
    __syncthreads();
  }

  // ---- epilogue (no barriers) ----
  const float g = gamma_p[0];
  const float c2 = g * 1.4426950408889634f;  // gamma * log2(e)

  float sv2v[2], dcv[2];
  const int colb = m0 + wave_m * 64 + l31;
  sv2v[0] = sv2[colb];
  dcv[0] = DC[colb];
  sv2v[1] = sv2[colb + 32];
  dcv[1] = DC[colb + 32];

#pragma unroll
  for (int i = 0; i < 2; ++i) {
    // C row = rowb + 8*g4 + r2, where reg = g4*4 + r2
    const int rowb = n0 + wave_n * 64 + i * 32 + 4 * lhi;
    float val[16];
#pragma unroll
    for (int g4 = 0; g4 < 4; ++g4) {
      f32x4 xv = *(const f32x4*)(x2 + rowb + 8 * g4);
#pragma unroll
      for (int r2 = 0; r2 < 4; ++r2) {
        const int reg = g4 * 4 + r2;
        float v = 0.0f;
#pragma unroll
        for (int j = 0; j < 2; ++j) {
          float d2 = xv[r2] + sv2v[j] - 2.0f * acc[i][j][reg];
          d2 = fmaxf(d2, 0.0f);
          v += exp2f(-c2 * d2) * dcv[j];
        }
        val[reg] = v;
      }
    }
    // reduce over the 32 column-lanes (lane bits 0..4)
#pragma unroll
    for (int m = 1; m < 32; m <<= 1)
#pragma unroll
      for (int reg = 0; reg < 16; ++reg)
        val[reg] += __shfl_xor(val[reg], m, 64);
    if (l31 == 0) {
#pragma unroll
      for (int g4 = 0; g4 < 4; ++g4)
#pragma unroll
        for (int r2 = 0; r2 < 4; ++r2)
          atomicAdd(&out[rowb + 8 * g4 + r2], val[g4 * 4 + r2]);
    }
  }
}

extern "C" void kernel_launch(void* const* d_in, const int* in_sizes, int n_in,
                              void* d_out, int out_size, void* d_ws, size_t ws_size,
                              hipStream_t stream) {
  const float* X = (const float*)d_in[0];
  const float* SV = (const float*)d_in[1];
  const float* DC = (const float*)d_in[2];
  const float* IC = (const float*)d_in[3];
  const float* gamma = (const float*)d_in[4];
  float* out = (float*)d_out;

  char* ws = (char*)d_ws;
  __bf16* Xb = (__bf16*)ws;                                   // 4 MB
  __bf16* SVb = (__bf16*)(ws + (size_t)NN * DD * 2);          // 8 MB
  float* x2 = (float*)(ws + (size_t)(NN + MM) * DD * 2);      // 16 KB
  float* sv2 = x2 + NN;                                       // 32 KB

  convert_norm_kernel<<<(NN + MM) / 4, 256, 0, stream>>>(X, SV, Xb, SVb, x2, sv2, out, IC);
  dim3 grid(NN / 128, MM / 128);
  rbf_gemm_kernel<<<grid, 256, 0, stream>>>((const bf16x8*)Xb, (const bf16x8*)SVb,
                                            x2, sv2, DC, gamma, out);
}

// Round 6
// 143.811 us; speedup vs baseline: 1.0049x; 1.0049x over previous
//
#include <hip/hip_runtime.h>
#include <stdint.h>

#define NN 4096
#define MM 8192
#define DD 512
#define KT3 16  // 512 / BK, BK = 32

typedef __bf16 bf16x8 __attribute__((ext_vector_type(8)));
typedef __bf16 bf16x4 __attribute__((ext_vector_type(4)));
typedef float f32x4 __attribute__((ext_vector_type(4)));
typedef float f32x16 __attribute__((ext_vector_type(16)));

__device__ __forceinline__ void load_lds16(const void* g, void* l) {
  // async global -> LDS, 16B/lane; LDS dest must be wave-uniform base + lane*16.
  __builtin_amdgcn_global_load_lds(
      (const __attribute__((address_space(1))) unsigned int*)g,
      (__attribute__((address_space(3))) unsigned int*)l, 16, 0, 0);
}

// 4 rows per 256-thread block, one wave per row. Fully-coalesced f32x4 loads,
// bf16x4 stores, exact fp32 row-norm, and out[]=IC init folded in.
__global__ __launch_bounds__(256) void convert_norm_kernel(
    const float* __restrict__ X, const float* __restrict__ SV,
    __bf16* __restrict__ Xb, __bf16* __restrict__ SVb,
    float* __restrict__ x2, float* __restrict__ sv2,
    float* __restrict__ out, const float* __restrict__ IC) {
  int wid = blockIdx.x * 4 + (threadIdx.x >> 6);
  int lane = threadIdx.x & 63;
  const float* src;
  __bf16* dst;
  float* nrm;
  if (wid < NN) {
    src = X + (size_t)wid * DD;
    dst = Xb + (size_t)wid * DD;
    nrm = x2 + wid;
    if (lane == 0) out[wid] = IC[0];
  } else {
    int r = wid - NN;
    src = SV + (size_t)r * DD;
    dst = SVb + (size_t)r * DD;
    nrm = sv2 + r;
  }
  const f32x4* s = (const f32x4*)src;
  f32x4 a = s[lane];
  f32x4 b = s[lane + 64];
  float sum = a.x * a.x + a.y * a.y + a.z * a.z + a.w * a.w +
              b.x * b.x + b.y * b.y + b.z * b.z + b.w * b.w;
  bf16x4 ca = {(__bf16)a.x, (__bf16)a.y, (__bf16)a.z, (__bf16)a.w};
  bf16x4 cb = {(__bf16)b.x, (__bf16)b.y, (__bf16)b.z, (__bf16)b.w};
  *(bf16x4*)(dst + 4 * lane) = ca;
  *(bf16x4*)(dst + 256 + 4 * lane) = cb;
#pragma unroll
  for (int m = 32; m >= 1; m >>= 1) sum += __shfl_xor(sum, m, 64);
  if (lane == 0) *nrm = sum;
}

// 256x128 tile, 8 waves (wave_n in 0..3, wave_m in 0..1), each wave 64x64 via
// 2x2 of mfma_f32_32x32x16_bf16. BK=32, DOUBLE-buffered LDS:
//   A 2x16 KB + B 2x8 KB = 48 KB -> 2 blocks/CU (reg-capped 4 waves/SIMD).
// Per kt: issue kt+1 loads into buf^1, compute kt, one barrier. The barrier's
// vmcnt(0) waits on loads issued a full compute phase earlier, and the second
// resident block covers the residue.
//
// LDS layout per buffer: rows x 4 chunks of 16 B, XOR swizzle:
//   P(row, kg) = row*4 + (kg ^ ((row>>1) & 3))
// Fragment read (32 consecutive rows, fixed kc): chunk mod 8 =
//   4*(row&1) + kc^((row>>1)&3) -> all 8 bank-groups x 4 lanes = balanced.
// Staging: chunk c -> row=c>>2, kg=(c&3)^((row>>1)&3); per 8-lane group the
// addresses permute two 64 B sectors -> coalesced; LDS dest lane-contiguous.
__global__ __launch_bounds__(512, 4) void rbf_gemm_kernel(
    const bf16x8* __restrict__ Xb, const bf16x8* __restrict__ SVb,
    const float* __restrict__ x2, const float* __restrict__ sv2,
    const float* __restrict__ DC, const float* __restrict__ gamma_p,
    float* __restrict__ out) {
  __shared__ bf16x8 As[2][1024];  // 2 x 16 KB (256 rows x 4 chunks)
  __shared__ bf16x8 Bs[2][512];   // 2 x 8 KB  (128 rows x 4 chunks)

  const int t = threadIdx.x;  // 0..511
  const int lane = t & 63;
  const int wave = t >> 6;    // 0..7
  const int n0 = blockIdx.x * 256;
  const int m0 = blockIdx.y * 128;

  const int wave_m = wave & 1;   // m-dir of C (0..1)
  const int wave_n = wave >> 1;  // n-dir of C (0..3)
  const int l31 = lane & 31;
  const int lhi = lane >> 5;

  // staging: A chunks cA0 = t, cA1 = t+512 (1024 chunks); B chunk cB0 = t (512)
  const int cA0 = t, cA1 = t + 512, cB0 = t;
  const int rA0 = cA0 >> 2, kA0 = (cA0 & 3) ^ ((rA0 >> 1) & 3);
  const int rA1 = cA1 >> 2, kA1 = (cA1 & 3) ^ ((rA1 >> 1) & 3);
  const int rB0 = cB0 >> 2, kB0 = (cB0 & 3) ^ ((rB0 >> 1) & 3);
  const size_t gA0 = (size_t)(n0 + rA0) * 64 + kA0;  // chunk index into Xb
  const size_t gA1 = (size_t)(n0 + rA1) * 64 + kA1;
  const size_t gB0 = (size_t)(m0 + rB0) * 64 + kB0;

  // fragment bases (chunk index); swizzle term depends only on l31
  const int ra4 = (wave_n * 64 + l31) * 4;
  const int rb4 = (wave_m * 64 + l31) * 4;
  const int swb = (l31 >> 1) & 3;

  f32x16 acc[2][2];
#pragma unroll
  for (int i = 0; i < 2; ++i)
#pragma unroll
    for (int j = 0; j < 2; ++j)
#pragma unroll
      for (int r = 0; r < 16; ++r) acc[i][j][r] = 0.0f;

  // prologue: stage kt=0 into buffer 0
  load_lds16(Xb + gA0, &As[0][cA0]);
  load_lds16(Xb + gA1, &As[0][cA1]);
  load_lds16(SVb + gB0, &Bs[0][cB0]);
  __syncthreads();

#pragma unroll
  for (int kt = 0; kt < KT3; ++kt) {
    const int cur = kt & 1;
    const int nxt = cur ^ 1;
    if (kt + 1 < KT3) {  // stage kt+1 (flies during compute below)
      const size_t ko = (size_t)(kt + 1) * 4;
      load_lds16(Xb + gA0 + ko, &As[nxt][cA0]);
      load_lds16(Xb + gA1 + ko, &As[nxt][cA1]);
      load_lds16(SVb + gB0 + ko, &Bs[nxt][cB0]);
    }
    // compute kt from buf[cur]
#pragma unroll
    for (int ks = 0; ks < 2; ++ks) {
      const int kc = ks * 2 + lhi;  // chunk 0..3
      const int sw = kc ^ swb;
      bf16x8 af0 = As[cur][ra4 + sw];
      bf16x8 af1 = As[cur][ra4 + 128 + sw];  // +32 rows
      bf16x8 bf0 = Bs[cur][rb4 + sw];
      bf16x8 bf1 = Bs[cur][rb4 + 128 + sw];
      acc[0][0] = __builtin_amdgcn_mfma_f32_32x32x16_bf16(af0, bf0, acc[0][0], 0, 0, 0);
      acc[0][1] = __builtin_amdgcn_mfma_f32_32x32x16_bf16(af0, bf1, acc[0][1], 0, 0, 0);
      acc[1][0] = __builtin_amdgcn_mfma_f32_32x32x16_bf16(af1, bf0, acc[1][0], 0, 0, 0);
      acc[1][1] = __builtin_amdgcn_mfma_f32_32x32x16_bf16(af1, bf1, acc[1][1], 0, 0, 0);
    }
    __syncthreads();
  }

  // ---- epilogue (no barriers) ----
  const float g = gamma_p[0];
  const float c2 = g * 1.4426950408889634f;  // gamma * log2(e)

  float sv2v[2], dcv[2];
  const int colb = m0 + wave_m * 64 + l31;
  sv2v[0] = sv2[colb];
  dcv[0] = DC[colb];
  sv2v[1] = sv2[colb + 32];
  dcv[1] = DC[colb + 32];

#pragma unroll
  for (int i = 0; i < 2; ++i) {
    // C row = rowb + 8*g4 + r2, where reg = g4*4 + r2
    const int rowb = n0 + wave_n * 64 + i * 32 + 4 * lhi;
    float val[16];
#pragma unroll
    for (int g4 = 0; g4 < 4; ++g4) {
      f32x4 xv = *(const f32x4*)(x2 + rowb + 8 * g4);
#pragma unroll
      for (int r2 = 0; r2 < 4; ++r2) {
        const int reg = g4 * 4 + r2;
        float v = 0.0f;
#pragma unroll
        for (int j = 0; j < 2; ++j) {
          float d2 = xv[r2] + sv2v[j] - 2.0f * acc[i][j][reg];
          d2 = fmaxf(d2, 0.0f);
          v += exp2f(-c2 * d2) * dcv[j];
        }
        val[reg] = v;
      }
    }
    // reduce over the 32 column-lanes (lane bits 0..4)
#pragma unroll
    for (int m = 1; m < 32; m <<= 1)
#pragma unroll
      for (int reg = 0; reg < 16; ++reg)
        val[reg] += __shfl_xor(val[reg], m, 64);
    if (l31 == 0) {
#pragma unroll
      for (int g4 = 0; g4 < 4; ++g4)
#pragma unroll
        for (int r2 = 0; r2 < 4; ++r2)
          atomicAdd(&out[rowb + 8 * g4 + r2], val[g4 * 4 + r2]);
    }
  }
}

extern "C" void kernel_launch(void* const* d_in, const int* in_sizes, int n_in,
                              void* d_out, int out_size, void* d_ws, size_t ws_size,
                              hipStream_t stream) {
  const float* X = (const float*)d_in[0];
  const float* SV = (const float*)d_in[1];
  const float* DC = (const float*)d_in[2];
  const float* IC = (const float*)d_in[3];
  const float* gamma = (const float*)d_in[4];
  float* out = (float*)d_out;

  char* ws = (char*)d_ws;
  __bf16* Xb = (__bf16*)ws;                                   // 4 MB
  __bf16* SVb = (__bf16*)(ws + (size_t)NN * DD * 2);          // 8 MB
  float* x2 = (float*)(ws + (size_t)(NN + MM) * DD * 2);      // 16 KB
  float* sv2 = x2 + NN;                                       // 32 KB

  convert_norm_kernel<<<(NN + MM) / 4, 256, 0, stream>>>(X, SV, Xb, SVb, x2, sv2, out, IC);
  dim3 grid(NN / 256, MM / 128);
  rbf_gemm_kernel<<<grid, 512, 0, stream>>>((const bf16x8*)Xb, (const bf16x8*)SVb,
                                            x2, sv2, DC, gamma, out);
}